// Round 5
// baseline (309.113 us; speedup 1.0000x reference)
//
#include <hip/hip_runtime.h>

// Wilson-Cowan-like rate recurrence, round 4 (resubmit — broker timeout).
//   u    = E[b,t,n] - r[n]*nu
//   phi  = M[n]*u/(u^2+sigma^2) * relu(u+th)
//   nu' = nu + (DT/tau)*(phi - nu)  ==  omc*nu + (cM*u*relu(u+th))*rcp(u^2+s2)
// with omc = 1-DT/tau, cM = (DT/tau)*M precomputed per thread.
//
// Round-3 evidence: 82.6 cyc/step; cost = 9 compute VALU + 4 VALU addr math
// + exposed latency. Fixes: (1) buffer ops with scalar soffset stepping
// (s_add on SALU pipe) -> zero per-step VALU address math; (2) parallel
// rcp/relu paths -> critical chain ~20 cy. Ring stays D=32: vmcnt is 6-bit
// and counts stores, so K=2(D-1)=62 is the max counted depth.

#define DT_STEP 0.1f

constexpr int Bc = 8;
constexpr int Tc = 4096;
constexpr int Nc = 1024;
constexpr int D  = 32;                 // loads in flight per lane

typedef int v4i __attribute__((ext_vector_type(4)));

__device__ __forceinline__ v4i make_srd(const void* p) {
    union { const void* p; unsigned long long u; } a; a.p = p;
    v4i r;
    r.x = (int)(a.u & 0xFFFFFFFFull);
    r.y = (int)((a.u >> 32) & 0xFFFFull);  // stride=0; high 16 addr bits
    r.z = (int)0xFFFFFFFFu;                // num_records: bounds check off
    r.w = 0x00020000;                      // raw untyped dword
    return r;
}

__global__ __launch_bounds__(64, 1) void cw_recurrence_kernel(
    const float* __restrict__ E,
    const float* __restrict__ r,
    const float* __restrict__ tau_nu,
    const float* __restrict__ M,
    const float* __restrict__ sigma,
    const float* __restrict__ th,
    float* __restrict__ out)
{
    const int idx = blockIdx.x * 64 + threadIdx.x;   // 0..8191
    const int b = idx >> 10;
    const int n = idx & (Nc - 1);

    const float rv   = r[n];
    const float coef = DT_STEP / tau_nu[n];
    const float cM   = coef * M[n];          // folds M and coef
    const float omc  = 1.0f - coef;          // decay factor
    const float sv   = sigma[n];
    const float s2   = sv * sv;
    const float thv  = th[n];

    const v4i rsE = make_srd(E);
    const v4i rsO = make_srd(out);
    // per-lane constant voffset; time dimension advances via scalar soffset
    const unsigned int voff = (unsigned int)((b * Tc * Nc + n) * 4);
    unsigned int soL = 0;                    // next load  soffset (t*Nc*4)
    unsigned int soS = 0;                    // next store soffset

    float nu = 0.0f;
    float buf[D];

    // ---- prologue: issue D loads (t = 0..31) ----
#pragma unroll
    for (int j = 0; j < D; ++j) {
        asm volatile("buffer_load_dword %0, %1, %2, %3 offen"
                     : "=v"(buf[j]) : "v"(voff), "s"(rsE), "s"(soL));
        soL += Nc * 4;
    }

    // Wait ties buf[slot] ("+v") so dependent compute can't hoist above it.
#define WAITK(K, slot) asm volatile("s_waitcnt vmcnt(" #K ")" : "+v"(buf[slot]))
#define BODY(slot) do {                                                   \
        float u   = fmaf(-rv, nu, buf[slot]);                             \
        float dd  = fmaf(u, u, s2);                                       \
        float inv = __builtin_amdgcn_rcpf(dd);   /* path A: 2 ops */      \
        float g   = fmaxf(u + thv, 0.0f);        /* path B: parallel */   \
        float cp  = (cM * u) * g;                                         \
        nu = fmaf(cp, inv, omc * nu);                                     \
        asm volatile("buffer_store_dword %0, %1, %2, %3 offen"            \
                     :: "v"(nu), "v"(voff), "s"(rsO), "s"(soS));          \
        soS += Nc * 4;                                                    \
    } while (0)
#define LOADQ(slot) do {                                                  \
        asm volatile("buffer_load_dword %0, %1, %2, %3 offen"             \
                     : "=v"(buf[slot]) : "v"(voff), "s"(rsE), "s"(soL));  \
        soL += Nc * 4;                                                    \
    } while (0)

#define SHEAD(j, K) WAITK(K, j); BODY(j); LOADQ(j);
#define SMAIN(j)    WAITK(62, j); BODY(j); LOADQ(j);
#define STAIL(j, K) WAITK(K, j); BODY(j);

    // ---- head block (t=0..31): K ramps 31 -> 62 ----
    SHEAD(0,31)  SHEAD(1,32)  SHEAD(2,33)  SHEAD(3,34)
    SHEAD(4,35)  SHEAD(5,36)  SHEAD(6,37)  SHEAD(7,38)
    SHEAD(8,39)  SHEAD(9,40)  SHEAD(10,41) SHEAD(11,42)
    SHEAD(12,43) SHEAD(13,44) SHEAD(14,45) SHEAD(15,46)
    SHEAD(16,47) SHEAD(17,48) SHEAD(18,49) SHEAD(19,50)
    SHEAD(20,51) SHEAD(21,52) SHEAD(22,53) SHEAD(23,54)
    SHEAD(24,55) SHEAD(25,56) SHEAD(26,57) SHEAD(27,58)
    SHEAD(28,59) SHEAD(29,60) SHEAD(30,61) SHEAD(31,62)

    // ---- steady blocks k = 1..126 (t = 32..4063): uniform K=62 ----
    for (int k = 1; k <= 126; ++k) {
        SMAIN(0)  SMAIN(1)  SMAIN(2)  SMAIN(3)
        SMAIN(4)  SMAIN(5)  SMAIN(6)  SMAIN(7)
        SMAIN(8)  SMAIN(9)  SMAIN(10) SMAIN(11)
        SMAIN(12) SMAIN(13) SMAIN(14) SMAIN(15)
        SMAIN(16) SMAIN(17) SMAIN(18) SMAIN(19)
        SMAIN(20) SMAIN(21) SMAIN(22) SMAIN(23)
        SMAIN(24) SMAIN(25) SMAIN(26) SMAIN(27)
        SMAIN(28) SMAIN(29) SMAIN(30) SMAIN(31)
    }

    // ---- tail block (t = 4064..4095): K ramps 62 -> 31 ----
    STAIL(0,62)  STAIL(1,61)  STAIL(2,60)  STAIL(3,59)
    STAIL(4,58)  STAIL(5,57)  STAIL(6,56)  STAIL(7,55)
    STAIL(8,54)  STAIL(9,53)  STAIL(10,52) STAIL(11,51)
    STAIL(12,50) STAIL(13,49) STAIL(14,48) STAIL(15,47)
    STAIL(16,46) STAIL(17,45) STAIL(18,44) STAIL(19,43)
    STAIL(20,42) STAIL(21,41) STAIL(22,40) STAIL(23,39)
    STAIL(24,38) STAIL(25,37) STAIL(26,36) STAIL(27,35)
    STAIL(28,34) STAIL(29,33) STAIL(30,32) STAIL(31,31)

#undef WAITK
#undef BODY
#undef LOADQ
#undef SHEAD
#undef SMAIN
#undef STAIL
}

extern "C" void kernel_launch(void* const* d_in, const int* in_sizes, int n_in,
                              void* d_out, int out_size, void* d_ws, size_t ws_size,
                              hipStream_t stream) {
    const float* E      = (const float*)d_in[0];
    const float* r      = (const float*)d_in[1];
    const float* tau_nu = (const float*)d_in[2];
    const float* M      = (const float*)d_in[3];
    const float* sigma  = (const float*)d_in[4];
    const float* th     = (const float*)d_in[5];
    float* out = (float*)d_out;

    const int total = Bc * Nc;        // 8192 independent sequences
    const int block = 64;             // 1 wave per block
    const int grid  = total / block;  // 128 blocks

    cw_recurrence_kernel<<<grid, block, 0, stream>>>(E, r, tau_nu, M, sigma, th, out);
}